// Round 1
// baseline (11208.750 us; speedup 1.0000x reference)
//
#include <hip/hip_runtime.h>
#include <math.h>

#define E_ 64
#define K_ 6
#define CAP_ 512
#define H_ 2048
#define I_ 768
#define SI_ 1536
#define T_ 2048

#define BM 32
#define BN 64
#define BK 32

__device__ __forceinline__ float silu(float v) {
    return v / (1.0f + expf(-v));
}

// ---------------- kernel 0: zero expert counts ----------------
__global__ void k_zero(int* __restrict__ counts) {
    if (threadIdx.x < E_) counts[threadIdx.x] = 0;
}

// ---------------- kernel 1: router (softmax + top-6 + dispatch) ----------------
__global__ __launch_bounds__(256) void k_router(const float* __restrict__ x,
                                                const float* __restrict__ gate_w,
                                                int* __restrict__ counts,
                                                int* __restrict__ buf_tok,
                                                float* __restrict__ buf_w) {
    const int t = blockIdx.x;
    const int tid = threadIdx.x;
    __shared__ float xs[H_];
    __shared__ float sc[E_];

    const float* xr = x + (size_t)t * H_;
    for (int h = tid * 4; h < H_; h += 256 * 4) {
        *(float4*)(xs + h) = *(const float4*)(xr + h);
    }
    __syncthreads();

    const int wave = tid >> 6;
    const int lane = tid & 63;
    // each wave computes 16 expert logits (64-lane dot + shuffle reduce)
    for (int i = 0; i < E_ / 4; ++i) {
        const int e = wave * (E_ / 4) + i;
        const float* w = gate_w + (size_t)e * H_;
        float s = 0.f;
        for (int h = lane; h < H_; h += 64) s += xs[h] * w[h];
        for (int off = 32; off > 0; off >>= 1) s += __shfl_down(s, off, 64);
        if (lane == 0) sc[e] = s;
    }
    __syncthreads();

    if (tid < 64) {
        float v = sc[tid];
        float m = v;
        for (int off = 32; off > 0; off >>= 1) m = fmaxf(m, __shfl_xor(m, off, 64));
        float ev = expf(v - m);
        float ssum = ev;
        for (int off = 32; off > 0; off >>= 1) ssum += __shfl_xor(ssum, off, 64);
        const float p = ev / ssum;   // softmax prob for expert `tid`
        float pv = p;
        for (int k = 0; k < K_; ++k) {
            float bm = pv;
            int bi = tid;
            for (int off = 32; off > 0; off >>= 1) {
                float om = __shfl_xor(bm, off, 64);
                int oi = __shfl_xor(bi, off, 64);
                if (om > bm || (om == bm && oi < bi)) { bm = om; bi = oi; }
            }
            if (tid == bi) pv = -1.f;  // remove winner (probs are >0)
            if (tid == 0) {
                int pos = atomicAdd(&counts[bi], 1);
                if (pos < CAP_) {
                    buf_tok[bi * CAP_ + pos] = t;
                    buf_w[bi * CAP_ + pos] = bm;   // SCALE == 1.0
                }
            }
        }
    }
}

// ---------------- kernel 2: routed experts gate_up GEMM + SwiGLU ----------------
// hid[e][c][i] = silu(X@Wg)[c][i] * (X@Wu)[c][i], X gathered per expert
__global__ __launch_bounds__(256) void k_gemm_gateup(const float* __restrict__ x,
                                                     const float* __restrict__ gup,   // [E][H][2I]
                                                     const int* __restrict__ counts,
                                                     const int* __restrict__ buf_tok,
                                                     float* __restrict__ hid) {       // [E][CAP][I]
    const int e = blockIdx.z;
    const int cnt = min(counts[e], CAP_);
    const int m0 = blockIdx.x * BM;
    if (m0 >= cnt) return;
    const int n0 = blockIdx.y * BN;       // over I
    const int tid = threadIdx.x;

    __shared__ float Xs[BK][BM + 1];
    __shared__ float Gs[BK][BN + 1];
    __shared__ float Us[BK][BN + 1];

    const int lm  = tid >> 3;             // 0..31 : m row for X load
    const int lk4 = (tid & 7) * 4;        // 0..28 : k base for X load
    const int tokm = (m0 + lm < cnt) ? buf_tok[e * CAP_ + m0 + lm] : -1;

    const int lkw = tid >> 3;             // 0..31 : k row for W load
    const int lnw = (tid & 7) * 8;        // 0..56 : n base for W load

    const int tm = tid >> 4;              // 0..15
    const int tn = tid & 15;              // 0..15

    float ag[2][4] = {{0.f}};
    float au[2][4] = {{0.f}};

    for (int k0 = 0; k0 < H_; k0 += BK) {
        __syncthreads();
        float4 xv = make_float4(0.f, 0.f, 0.f, 0.f);
        if (tokm >= 0) xv = *(const float4*)(x + (size_t)tokm * H_ + k0 + lk4);
        Xs[lk4 + 0][lm] = xv.x; Xs[lk4 + 1][lm] = xv.y;
        Xs[lk4 + 2][lm] = xv.z; Xs[lk4 + 3][lm] = xv.w;

        const float* wr = gup + ((size_t)e * H_ + k0 + lkw) * (2 * I_);
        float4 g0 = *(const float4*)(wr + n0 + lnw);
        float4 g1 = *(const float4*)(wr + n0 + lnw + 4);
        float4 u0 = *(const float4*)(wr + I_ + n0 + lnw);
        float4 u1 = *(const float4*)(wr + I_ + n0 + lnw + 4);
        Gs[lkw][lnw + 0] = g0.x; Gs[lkw][lnw + 1] = g0.y; Gs[lkw][lnw + 2] = g0.z; Gs[lkw][lnw + 3] = g0.w;
        Gs[lkw][lnw + 4] = g1.x; Gs[lkw][lnw + 5] = g1.y; Gs[lkw][lnw + 6] = g1.z; Gs[lkw][lnw + 7] = g1.w;
        Us[lkw][lnw + 0] = u0.x; Us[lkw][lnw + 1] = u0.y; Us[lkw][lnw + 2] = u0.z; Us[lkw][lnw + 3] = u0.w;
        Us[lkw][lnw + 4] = u1.x; Us[lkw][lnw + 5] = u1.y; Us[lkw][lnw + 6] = u1.z; Us[lkw][lnw + 7] = u1.w;
        __syncthreads();

#pragma unroll
        for (int kk = 0; kk < BK; ++kk) {
            float x0 = Xs[kk][tm * 2 + 0];
            float x1 = Xs[kk][tm * 2 + 1];
            float g[4], u[4];
#pragma unroll
            for (int j = 0; j < 4; ++j) { g[j] = Gs[kk][tn * 4 + j]; u[j] = Us[kk][tn * 4 + j]; }
#pragma unroll
            for (int j = 0; j < 4; ++j) {
                ag[0][j] += x0 * g[j]; ag[1][j] += x1 * g[j];
                au[0][j] += x0 * u[j]; au[1][j] += x1 * u[j];
            }
        }
    }

#pragma unroll
    for (int i = 0; i < 2; ++i) {
        const int m = m0 + tm * 2 + i;
        if (m < cnt) {
            float4 o;
            o.x = silu(ag[i][0]) * au[i][0];
            o.y = silu(ag[i][1]) * au[i][1];
            o.z = silu(ag[i][2]) * au[i][2];
            o.w = silu(ag[i][3]) * au[i][3];
            *(float4*)(hid + ((size_t)e * CAP_ + m) * I_ + n0 + tn * 4) = o;
        }
    }
}

// ---------------- kernel 3: shared expert gate/up GEMM + SwiGLU ----------------
__global__ __launch_bounds__(256) void k_shared_gateup(const float* __restrict__ x,   // [T][H]
                                                       const float* __restrict__ wg,  // [SI][H]
                                                       const float* __restrict__ wu,  // [SI][H]
                                                       float* __restrict__ hid) {     // [T][SI]
    const int m0 = blockIdx.x * BM;
    const int n0 = blockIdx.y * BN;       // over SI
    const int tid = threadIdx.x;

    __shared__ float Xs[BK][BM + 1];
    __shared__ float Gs[BK][BN + 1];
    __shared__ float Us[BK][BN + 1];

    const int lm  = tid >> 3;
    const int lk4 = (tid & 7) * 4;
    const int ln  = tid >> 2;             // 0..63 : n row (W is [SI][H], transposed load)
    const int lk8 = (tid & 3) * 8;        // 0,8,16,24

    const int tm = tid >> 4;
    const int tn = tid & 15;

    float ag[2][4] = {{0.f}};
    float au[2][4] = {{0.f}};

    for (int k0 = 0; k0 < H_; k0 += BK) {
        __syncthreads();
        float4 xv = *(const float4*)(x + (size_t)(m0 + lm) * H_ + k0 + lk4);
        Xs[lk4 + 0][lm] = xv.x; Xs[lk4 + 1][lm] = xv.y;
        Xs[lk4 + 2][lm] = xv.z; Xs[lk4 + 3][lm] = xv.w;

        const float* gr = wg + (size_t)(n0 + ln) * H_ + k0 + lk8;
        const float* ur = wu + (size_t)(n0 + ln) * H_ + k0 + lk8;
        float4 g0 = *(const float4*)(gr);
        float4 g1 = *(const float4*)(gr + 4);
        float4 u0 = *(const float4*)(ur);
        float4 u1 = *(const float4*)(ur + 4);
        Gs[lk8 + 0][ln] = g0.x; Gs[lk8 + 1][ln] = g0.y; Gs[lk8 + 2][ln] = g0.z; Gs[lk8 + 3][ln] = g0.w;
        Gs[lk8 + 4][ln] = g1.x; Gs[lk8 + 5][ln] = g1.y; Gs[lk8 + 6][ln] = g1.z; Gs[lk8 + 7][ln] = g1.w;
        Us[lk8 + 0][ln] = u0.x; Us[lk8 + 1][ln] = u0.y; Us[lk8 + 2][ln] = u0.z; Us[lk8 + 3][ln] = u0.w;
        Us[lk8 + 4][ln] = u1.x; Us[lk8 + 5][ln] = u1.y; Us[lk8 + 6][ln] = u1.z; Us[lk8 + 7][ln] = u1.w;
        __syncthreads();

#pragma unroll
        for (int kk = 0; kk < BK; ++kk) {
            float x0 = Xs[kk][tm * 2 + 0];
            float x1 = Xs[kk][tm * 2 + 1];
            float g[4], u[4];
#pragma unroll
            for (int j = 0; j < 4; ++j) { g[j] = Gs[kk][tn * 4 + j]; u[j] = Us[kk][tn * 4 + j]; }
#pragma unroll
            for (int j = 0; j < 4; ++j) {
                ag[0][j] += x0 * g[j]; ag[1][j] += x1 * g[j];
                au[0][j] += x0 * u[j]; au[1][j] += x1 * u[j];
            }
        }
    }

#pragma unroll
    for (int i = 0; i < 2; ++i) {
        const int m = m0 + tm * 2 + i;
        float4 o;
        o.x = silu(ag[i][0]) * au[i][0];
        o.y = silu(ag[i][1]) * au[i][1];
        o.z = silu(ag[i][2]) * au[i][2];
        o.w = silu(ag[i][3]) * au[i][3];
        *(float4*)(hid + (size_t)m * SI_ + n0 + tn * 4) = o;
    }
}

// ---------------- kernel 4: shared expert down GEMM (plain store -> init out) ----------------
__global__ __launch_bounds__(256) void k_shared_down(const float* __restrict__ hid,  // [T][SI]
                                                     const float* __restrict__ wd,   // [H][SI]
                                                     float* __restrict__ out) {      // [T][H]
    const int m0 = blockIdx.x * BM;
    const int n0 = blockIdx.y * BN;       // over H
    const int tid = threadIdx.x;

    __shared__ float As[BK][BM + 1];
    __shared__ float Ds[BK][BN + 1];

    const int lm  = tid >> 3;
    const int lk4 = (tid & 7) * 4;
    const int ln  = tid >> 2;
    const int lk8 = (tid & 3) * 8;

    const int tm = tid >> 4;
    const int tn = tid & 15;

    float acc[2][4] = {{0.f}};

    for (int k0 = 0; k0 < SI_; k0 += BK) {
        __syncthreads();
        float4 av = *(const float4*)(hid + (size_t)(m0 + lm) * SI_ + k0 + lk4);
        As[lk4 + 0][lm] = av.x; As[lk4 + 1][lm] = av.y;
        As[lk4 + 2][lm] = av.z; As[lk4 + 3][lm] = av.w;

        const float* dr = wd + (size_t)(n0 + ln) * SI_ + k0 + lk8;
        float4 d0 = *(const float4*)(dr);
        float4 d1 = *(const float4*)(dr + 4);
        Ds[lk8 + 0][ln] = d0.x; Ds[lk8 + 1][ln] = d0.y; Ds[lk8 + 2][ln] = d0.z; Ds[lk8 + 3][ln] = d0.w;
        Ds[lk8 + 4][ln] = d1.x; Ds[lk8 + 5][ln] = d1.y; Ds[lk8 + 6][ln] = d1.z; Ds[lk8 + 7][ln] = d1.w;
        __syncthreads();

#pragma unroll
        for (int kk = 0; kk < BK; ++kk) {
            float a0 = As[kk][tm * 2 + 0];
            float a1 = As[kk][tm * 2 + 1];
            float d[4];
#pragma unroll
            for (int j = 0; j < 4; ++j) d[j] = Ds[kk][tn * 4 + j];
#pragma unroll
            for (int j = 0; j < 4; ++j) {
                acc[0][j] += a0 * d[j];
                acc[1][j] += a1 * d[j];
            }
        }
    }

#pragma unroll
    for (int i = 0; i < 2; ++i) {
        const int m = m0 + tm * 2 + i;
        float4 o;
        o.x = acc[i][0]; o.y = acc[i][1]; o.z = acc[i][2]; o.w = acc[i][3];
        *(float4*)(out + (size_t)m * H_ + n0 + tn * 4) = o;
    }
}

// ---------------- kernel 5: routed experts down GEMM + weighted scatter-add ----------------
__global__ __launch_bounds__(256) void k_gemm_down(const float* __restrict__ hid,    // [E][CAP][I]
                                                   const float* __restrict__ dwn,    // [E][I][H]
                                                   const int* __restrict__ counts,
                                                   const int* __restrict__ buf_tok,
                                                   const float* __restrict__ buf_w,
                                                   float* __restrict__ out) {        // [T][H]
    const int e = blockIdx.z;
    const int cnt = min(counts[e], CAP_);
    const int m0 = blockIdx.x * BM;
    if (m0 >= cnt) return;
    const int n0 = blockIdx.y * BN;       // over H
    const int tid = threadIdx.x;

    __shared__ float As[BK][BM + 1];
    __shared__ float Ds[BK][BN + 1];

    const int lm  = tid >> 3;
    const int lk4 = (tid & 7) * 4;
    const int lkw = tid >> 3;
    const int lnw = (tid & 7) * 8;

    const int tm = tid >> 4;
    const int tn = tid & 15;

    float acc[2][4] = {{0.f}};

    for (int k0 = 0; k0 < I_; k0 += BK) {
        __syncthreads();
        float4 av = make_float4(0.f, 0.f, 0.f, 0.f);
        if (m0 + lm < cnt) av = *(const float4*)(hid + ((size_t)e * CAP_ + m0 + lm) * I_ + k0 + lk4);
        As[lk4 + 0][lm] = av.x; As[lk4 + 1][lm] = av.y;
        As[lk4 + 2][lm] = av.z; As[lk4 + 3][lm] = av.w;

        const float* dr = dwn + ((size_t)e * I_ + k0 + lkw) * H_ + n0 + lnw;
        float4 d0 = *(const float4*)(dr);
        float4 d1 = *(const float4*)(dr + 4);
        Ds[lkw][lnw + 0] = d0.x; Ds[lkw][lnw + 1] = d0.y; Ds[lkw][lnw + 2] = d0.z; Ds[lkw][lnw + 3] = d0.w;
        Ds[lkw][lnw + 4] = d1.x; Ds[lkw][lnw + 5] = d1.y; Ds[lkw][lnw + 6] = d1.z; Ds[lkw][lnw + 7] = d1.w;
        __syncthreads();

#pragma unroll
        for (int kk = 0; kk < BK; ++kk) {
            float a0 = As[kk][tm * 2 + 0];
            float a1 = As[kk][tm * 2 + 1];
            float d[4];
#pragma unroll
            for (int j = 0; j < 4; ++j) d[j] = Ds[kk][tn * 4 + j];
#pragma unroll
            for (int j = 0; j < 4; ++j) {
                acc[0][j] += a0 * d[j];
                acc[1][j] += a1 * d[j];
            }
        }
    }

#pragma unroll
    for (int i = 0; i < 2; ++i) {
        const int m = m0 + tm * 2 + i;
        if (m < cnt) {
            const int tok = buf_tok[e * CAP_ + m];
            const float w = buf_w[e * CAP_ + m];
            float* orow = out + (size_t)tok * H_ + n0 + tn * 4;
#pragma unroll
            for (int j = 0; j < 4; ++j) atomicAdd(orow + j, acc[i][j] * w);
        }
    }
}

extern "C" void kernel_launch(void* const* d_in, const int* in_sizes, int n_in,
                              void* d_out, int out_size, void* d_ws, size_t ws_size,
                              hipStream_t stream) {
    const float* x      = (const float*)d_in[0];
    const float* gate_w = (const float*)d_in[1];
    const float* gup    = (const float*)d_in[2];
    const float* dwn    = (const float*)d_in[3];
    const float* swg    = (const float*)d_in[4];
    const float* swu    = (const float*)d_in[5];
    const float* swd    = (const float*)d_in[6];
    float* out = (float*)d_out;

    // workspace layout
    int* counts   = (int*)d_ws;                        // [E]
    int* buf_tok  = counts + 64;                       // [E*CAP]
    float* buf_w  = (float*)(buf_tok + E_ * CAP_);     // [E*CAP]
    float* hid_r  = buf_w + E_ * CAP_;                 // [E*CAP*I]
    float* hid_s  = hid_r + (size_t)E_ * CAP_ * I_;    // [T*SI]

    hipLaunchKernelGGL(k_zero, dim3(1), dim3(64), 0, stream, counts);
    hipLaunchKernelGGL(k_router, dim3(T_), dim3(256), 0, stream,
                       x, gate_w, counts, buf_tok, buf_w);
    hipLaunchKernelGGL(k_gemm_gateup, dim3(CAP_ / BM, I_ / BN, E_), dim3(256), 0, stream,
                       x, gup, counts, buf_tok, hid_r);
    hipLaunchKernelGGL(k_shared_gateup, dim3(T_ / BM, SI_ / BN), dim3(256), 0, stream,
                       x, swg, swu, hid_s);
    hipLaunchKernelGGL(k_shared_down, dim3(T_ / BM, H_ / BN), dim3(256), 0, stream,
                       hid_s, swd, out);
    hipLaunchKernelGGL(k_gemm_down, dim3(CAP_ / BM, H_ / BN, E_), dim3(256), 0, stream,
                       hid_r, dwn, counts, buf_tok, buf_w, out);
}